// Round 19
// baseline (3524.347 us; speedup 1.0000x reference)
//
#include <hip/hip_runtime.h>
#include <cstdint>

// ---------------------------------------------------------------------------
// 3-layer LSTM (B=32, T=1024, H=I=512), PyTorch gate order (i,f,g,o).
// ROUND 19: tail-poll + dual prefetch (A and B both issued at step tail).
// r18 analysis: own-poll DETECT (not just A retire) sits on the chain.
// The own-poll condition for step ts ("all 32 WGs published h(ts-1)") can be
// polled at the TAIL of step ts-1 (right after our publish) with identical
// semantics; A-loads then issue at the tail and retire under the next step's
// stage+MFMA-B. Step head: vmcnt -> stage A+B -> sync -> 32 MFMA -> gates ->
// publish. Tail: flag -> B-poll/B-issue -> own-poll/A-issue (B retire
// overlaps own-poll). Throttle moved to just before publish (every 8 steps;
// proof unchanged -- later check = more downstream slack).
// Everything else identical to r18 (verified 3.18ms / 2.44e-4).
// Predicted: step ~2.6-2.8us, total ~2.75-2.95ms. If <5% gain: roofline.
// ---------------------------------------------------------------------------

typedef unsigned short u16;
typedef _Float16 f16;
typedef f16 f16x8 __attribute__((ext_vector_type(8)));
typedef unsigned short ushort8 __attribute__((ext_vector_type(8)));
typedef float f32x4 __attribute__((ext_vector_type(4)));

#define NB 32
#define NT 1024
#define NH 512
#define N4H 2048
#define RR 16     // hring depth (power of 2)
#define MROWS (NB * NT)
#define HBUFB 8192  // u16 offset of operand-B buffer in hbuf

__device__ __forceinline__ float sigm(float x) { return 1.f / (1.f + __expf(-x)); }
__device__ __forceinline__ float tanh_s(float x) {
  float a = fabsf(x);
  float e = __expf(-2.f * a);
  float t = (1.f - e) / (1.f + e);
  return copysignf(t, x);
}

// --- per-instruction device-coherent (IC-level) accessors ---
__device__ __forceinline__ void ld16_sc(const u16* p, uint4& d) {
  asm volatile("global_load_dwordx4 %0, %1, off sc0 sc1" : "=v"(d) : "v"(p));
}
__device__ __forceinline__ int ldf(const int* p) {
  int r;
  asm volatile("global_load_dword %0, %1, off sc0 sc1\n\ts_waitcnt vmcnt(0)"
               : "=v"(r) : "v"(p) : "memory");
  return r;
}
__device__ __forceinline__ void st16b_sc(u16* p, unsigned v) {
  asm volatile("global_store_short %0, %1, off sc0 sc1" :: "v"(p), "v"(v) : "memory");
}
__device__ __forceinline__ void st32b_sc(int* p, int v) {
  asm volatile("global_store_dword %0, %1, off sc0 sc1" :: "v"(p), "v"(v) : "memory");
}

// X [32,4,1024,128] f32 -> xs[n=b*1024+t][512] fp16
__global__ void k_gather_x(const float* __restrict__ X, u16* __restrict__ xs) {
  int64_t i = (int64_t)blockIdx.x * 256 + threadIdx.x;  // 16,777,216
  int k = (int)(i & 511);
  int t = (int)((i >> 9) & 1023);
  int b = (int)(i >> 19);
  int c = k >> 7, f = k & 127;
  float v = X[(((int64_t)(b * 4 + c) * 1024 + t) << 7) + f];
  f16 hv = (f16)v;
  xs[((int64_t)b * 1024 + t) * 512 + k] = *(u16*)&hv;
}

// W [2048,512] f32 -> Wp[2048][512] fp16
__global__ void k_split_w(const float* __restrict__ W, u16* __restrict__ Wp) {
  int i = blockIdx.x * 256 + threadIdx.x;  // 1,048,576
  f16 hv = (f16)W[i];
  Wp[i] = *(u16*)&hv;
}

__global__ void k_bias(const float* __restrict__ bi, const float* __restrict__ bh,
                       float* __restrict__ bo) {
  int i = blockIdx.x * 256 + threadIdx.x;
  if (i < N4H) bo[i] = bi[i] + bh[i];
}

// ---------------------------------------------------------------------------
// Single-launch pipelined 3-layer LSTM, fp16. 192 WGs x 256 thr.
// wg: l=wg>>6; wgl=wg&63; bg=wgl>>5; ugg=wgl&31.  [r15..r18-verified]
// Wave w: M-tile rows tr=lane&15 -> (gate=tr&3, u_row=tr>>2); lane owns
// (unit=ugg*16+w*4+q, batch=bg*16+cb), q=lane>>4, cb=lane&15.
// Step ts: gates = bias + W_in*input(ts) + W_hh*h_l(ts-1);
//   input = xs(ts) [l=0] or hring[l-1][ts&15] [l>0], batches bg*16..+15.
// hbuf: A @0, B @HBUFB; 16 rows x 512 f16, XOR-swz by (row&7)<<3.
// wlds: W_in row r=w*16+tr at r*512 f16, elems swz by ((tr&7)<<3).
// ---------------------------------------------------------------------------
__launch_bounds__(256, 1)
__global__ void k_lstm3(const float* __restrict__ Whh0, const float* __restrict__ Whh1,
                        const float* __restrict__ Whh2,
                        const u16* __restrict__ Wp0, const u16* __restrict__ Wp1,
                        const u16* __restrict__ Wp2,
                        const float* __restrict__ bias0, const float* __restrict__ bias1,
                        const float* __restrict__ bias2,
                        const u16* __restrict__ xs, u16* __restrict__ hring,
                        u16* __restrict__ hfinal, int* __restrict__ flags) {
  __shared__ u16 wlds[32768];  // W_in fp16: 64 rows x 512, swz (64KB)
  __shared__ u16 hbuf[16384];  // A @0, B @8192: 16 rows x 512 f16, swz (32KB)
  const int tid = threadIdx.x;
  const int lane = tid & 63;
  const int w = tid >> 6;
  const int wg = blockIdx.x;
  const int l = wg >> 6;
  const int wgl = wg & 63;
  const int bg = wgl >> 5;
  const int ugg = wgl & 31;
  const int q = lane >> 4;
  const int cb = lane & 15;
  const int tr = lane & 15;

  const float* Whh = (l == 0) ? Whh0 : (l == 1) ? Whh1 : Whh2;
  const u16* Wp = (l == 0) ? Wp0 : (l == 1) ? Wp1 : Wp2;
  const float* bs = (l == 0) ? bias0 : (l == 1) ? bias1 : bias2;

  // this lane's A-row: gate=tr&3, u_row=tr>>2
  const int64_t grow = (int64_t)(tr & 3) * 512 + ugg * 16 + w * 4 + (tr >> 2);

  // --- W_hh fp16 frags into registers (64 VGPR) ---
  f16x8 whh[16];
  {
    const float* wsrc = Whh + grow * 512 + q * 8;
#pragma unroll
    for (int kk = 0; kk < 16; ++kk) {
      float4 a = *(const float4*)(wsrc + kk * 32);
      float4 b = *(const float4*)(wsrc + kk * 32 + 4);
      f16x8 hv;
      hv[0] = (f16)a.x; hv[1] = (f16)a.y; hv[2] = (f16)a.z; hv[3] = (f16)a.w;
      hv[4] = (f16)b.x; hv[5] = (f16)b.y; hv[6] = (f16)b.z; hv[7] = (f16)b.w;
      whh[kk] = hv;
    }
  }

  // --- W_in fp16 into wlds: row r=w*16+tr at r*512, elems ^((tr&7)<<3) ---
  {
#pragma unroll
    for (int i = 0; i < 16; ++i) {
      int c = tid + i * 256;          // 4096 chunks of 8 f16
      int r = c >> 6;                 // 0..63
      int kc = (c & 63) * 8;          // 0..504
      int tr2 = r & 15;
      int64_t gr = (int64_t)(tr2 & 3) * 512 + ugg * 16 + (r >> 4) * 4 + (tr2 >> 2);
      ushort8 v = *(const ushort8*)(Wp + gr * 512 + kc);
      *(ushort8*)&wlds[r * 512 + (kc ^ ((tr2 & 7) << 3))] = v;
    }
  }
  __syncthreads();

  const int bat = bg * 16 + cb;              // this lane's batch
  const int ucol = ugg * 16 + w * 4 + q;     // this lane's unit
  const float b0 = bs[ucol], b1 = bs[512 + ucol], b2 = bs[1024 + ucol],
              b3 = bs[1536 + ucol];
  float cst = 0.f;

  int* fl_own = flags + l * 64 + bg * 32;
  int* fl_up = flags + (l - 1) * 64 + bg * 32;
  int* fl_dn = flags + (l + 1) * 64 + bg * 32;
  const int wrow = (w * 16 + tr) * 512;      // lane's W_in LDS row base
  const int wswz = (tr & 7) << 3;
  const int hswz = (cb & 7) << 3;
  const int hrbA = cb * 512;
  const int hrbB = HBUFB + cb * 512;

  // per-thread staging chunk coords (4 chunks of 8 f16 each)
  int sbv[4], sov[4];
#pragma unroll
  for (int i = 0; i < 4; ++i) {
    int c = tid + i * 256;
    sbv[i] = c >> 6;
    sov[i] = (c & 63) * 8;
  }

  // --- prologue: prefetch B(0) into registers ---
  uint4 vB[4], vA[4];
  if (l > 0) {  // upstream must have published h(0)
    int gd = 0;
    for (;;) {
      if (__all((int)(ldf(fl_up + (lane & 31)) >= 1))) break;
      __builtin_amdgcn_s_sleep(1);
      if (++gd > (1 << 14)) break;
    }
    const u16* srcB = hring + ((int64_t)((l - 1) * RR) * NB + bg * 16) * 512;
#pragma unroll
    for (int i = 0; i < 4; ++i) ld16_sc(srcB + sbv[i] * 512 + sov[i], vB[i]);
  } else {
    const u16* srcB = xs + ((int64_t)(bg * 16) * NT) * 512;
#pragma unroll
    for (int i = 0; i < 4; ++i)
      ld16_sc(srcB + (int64_t)sbv[i] * NT * 512 + sov[i], vB[i]);
  }

  for (int ts = 0; ts < NT; ++ts) {
    // --- head: all operands (vB, and vA for ts>0) already in flight ---
    asm volatile("s_waitcnt vmcnt(0)" ::: "memory");
    __builtin_amdgcn_sched_barrier(0);
#pragma unroll
    for (int i = 0; i < 4; ++i)
      *(uint4*)&hbuf[HBUFB + sbv[i] * 512 + (sov[i] ^ ((sbv[i] & 7) << 3))] = vB[i];
    if (ts > 0) {
#pragma unroll
      for (int i = 0; i < 4; ++i)
        *(uint4*)&hbuf[sbv[i] * 512 + (sov[i] ^ ((sbv[i] & 7) << 3))] = vA[i];
    }
    __syncthreads();

    f32x4 acc = {0.f, 0.f, 0.f, 0.f};
#pragma unroll
    for (int kk = 0; kk < 16; ++kk) {
      const int kv = kk * 32 + q * 8;
      f16x8 wv = *(const f16x8*)&wlds[wrow + (kv ^ wswz)];
      f16x8 xv = *(const f16x8*)&hbuf[hrbB + (kv ^ hswz)];
      acc = __builtin_amdgcn_mfma_f32_16x16x32_f16(wv, xv, acc, 0, 0, 0);
    }
    if (ts > 0) {
#pragma unroll
      for (int kk = 0; kk < 16; ++kk) {
        const int kidx = (kk * 32 + q * 8) ^ hswz;
        f16x8 hv = *(const f16x8*)&hbuf[hrbA + kidx];
        acc = __builtin_amdgcn_mfma_f32_16x16x32_f16(whh[kk], hv, acc, 0, 0, 0);
      }
    }

    // --- gates + state ---
    float ip = acc[0] + b0;
    float fp = acc[1] + b1;
    float gg = acc[2] + b2;
    float op = acc[3] + b3;
    float i_s = sigm(ip), f_s = sigm(fp), g_t = tanh_s(gg), o_s = sigm(op);
    cst = f_s * cst + i_s * g_t;
    float h = o_s * tanh_s(cst);

    // --- downstream throttle (ring WAR, RR=16): before publish, every 8 ---
    if (l < 2 && (ts & 7) == 0 && ts > 0) {
      int gd = 0;
      for (;;) {
        if (__all((int)(ldf(fl_dn + (lane & 31)) >= ts - 8))) break;
        __builtin_amdgcn_s_sleep(1);
        if (++gd > (1 << 14)) break;  // anomaly: fail fast to wrong output
      }
    }

    // --- publish h(ts) ---
    f16 hf = (f16)h;
    u16 hbits = *(u16*)&hf;
    u16* hw = hring + ((int64_t)(l * RR + (ts & (RR - 1))) * NB + bat) * 512 + ucol;
    st16b_sc(hw, (unsigned)hbits);
    if (l == 2 && ts == NT - 1) hfinal[bat * 512 + ucol] = hbits;
    asm volatile("s_waitcnt vmcnt(0)" ::: "memory");  // h at IC
    __syncthreads();  // all waves done (also fences hbuf for next step)
    if (tid == 0) st32b_sc(flags + l * 64 + bg * 32 + ugg, ts + 1);

    // --- tail prefetch for ts+1: B first (retire overlaps own-poll), then A
    if (ts + 1 < NT) {
      if (l > 0) {  // B: upstream h(ts+1) (steady state: flag already set)
        int gd = 0;
        for (;;) {
          if (__all((int)(ldf(fl_up + (lane & 31)) >= ts + 2))) break;
          __builtin_amdgcn_s_sleep(1);
          if (++gd > (1 << 14)) break;
        }
        const u16* srcB = hring + ((int64_t)((l - 1) * RR + ((ts + 1) & (RR - 1))) * NB
                                   + bg * 16) * 512;
#pragma unroll
        for (int i = 0; i < 4; ++i) ld16_sc(srcB + sbv[i] * 512 + sov[i], vB[i]);
      } else {
        const u16* srcB = xs + ((int64_t)(bg * 16) * NT + (ts + 1)) * 512;
#pragma unroll
        for (int i = 0; i < 4; ++i)
          ld16_sc(srcB + (int64_t)sbv[i] * NT * 512 + sov[i], vB[i]);
      }
      // A: own h(ts) -- poll all 32 own WGs published, then issue. Identical
      // dependency edge as the old head-poll; retire overlaps next head.
      {
        int gd = 0;
        for (;;) {
          if (__all((int)(ldf(fl_own + (lane & 31)) >= ts + 1))) break;
          __builtin_amdgcn_s_sleep(1);
          if (++gd > (1 << 14)) break;  // anomaly: fail fast to wrong output
        }
        const u16* srcA = hring + ((int64_t)(l * RR + (ts & (RR - 1))) * NB
                                   + bg * 16) * 512;
#pragma unroll
        for (int i = 0; i < 4; ++i) ld16_sc(srcA + sbv[i] * 512 + sov[i], vA[i]);
      }
    }
  }
}

// out[32,80] = hfinal(fp16) @ W_out^T + b_out
__global__ void k_final(const u16* __restrict__ hfinal, const float* __restrict__ Wout,
                        const float* __restrict__ bout, float* __restrict__ out) {
  const int b = blockIdx.x;
  const int o = threadIdx.x;
  if (o >= 80) return;
  const u16* hp = hfinal + b * 512;
  float acc = bout[o];
  for (int k = 0; k < 512; ++k) {
    f16 hv = *(const f16*)&hp[k];
    acc += (float)hv * Wout[o * 512 + k];
  }
  out[b * 80 + o] = acc;
}

extern "C" void kernel_launch(void* const* d_in, const int* in_sizes, int n_in,
                              void* d_out, int out_size, void* d_ws, size_t ws_size,
                              hipStream_t stream) {
  const float* X = (const float*)d_in[0];
  const float* Wih[3] = {(const float*)d_in[1], (const float*)d_in[5], (const float*)d_in[9]};
  const float* Whh[3] = {(const float*)d_in[2], (const float*)d_in[6], (const float*)d_in[10]};
  const float* bih[3] = {(const float*)d_in[3], (const float*)d_in[7], (const float*)d_in[11]};
  const float* bhh[3] = {(const float*)d_in[4], (const float*)d_in[8], (const float*)d_in[12]};
  const float* Wout = (const float*)d_in[13];
  const float* bout = (const float*)d_in[14];
  float* out = (float*)d_out;

  char* ws = (char*)d_ws;
  size_t off = 0;
  auto alloc = [&](size_t bytes) {
    char* p = ws + off;
    off = (off + bytes + 255) & ~(size_t)255;
    return p;
  };
  u16* xs = (u16*)alloc((size_t)MROWS * 512 * 2);          // 32 MiB
  u16* Wp[3];
  for (int l = 0; l < 3; ++l) Wp[l] = (u16*)alloc((size_t)N4H * 512 * 2);  // 2 MiB each
  float* bias[3];
  for (int l = 0; l < 3; ++l) bias[l] = (float*)alloc(N4H * 4);
  u16* hring = (u16*)alloc((size_t)3 * RR * NB * 512 * 2); // 1.5 MiB
  u16* hfinal = (u16*)alloc(NB * 512 * 2);                 // 32 KiB
  int* flags = (int*)alloc(3 * 64 * 4);                    // 768 B
  // total ~39.6 MiB

  hipMemsetAsync(flags, 0, 3 * 64 * 4, stream);
  k_gather_x<<<65536, 256, 0, stream>>>(X, xs);
  for (int l = 0; l < 3; ++l) {
    k_split_w<<<4096, 256, 0, stream>>>(Wih[l], Wp[l]);
    k_bias<<<8, 256, 0, stream>>>(bih[l], bhh[l], bias[l]);
  }

  k_lstm3<<<192, 256, 0, stream>>>(Whh[0], Whh[1], Whh[2],
                                   Wp[0], Wp[1], Wp[2],
                                   bias[0], bias[1], bias[2],
                                   xs, hring, hfinal, flags);

  k_final<<<32, 128, 0, stream>>>(hfinal, Wout, bout, out);
}

// Round 20
// 3178.921 us; speedup vs baseline: 1.1087x; 1.1087x over previous
//
#include <hip/hip_runtime.h>
#include <cstdint>

// ---------------------------------------------------------------------------
// 3-layer LSTM (B=32, T=1024, H=I=512), PyTorch gate order (i,f,g,o).
// ROUND 20 = r18 restored (best verified: 3.18ms, absmax 2.44e-4).
// r19's tail-poll regressed (3.52ms): issuing A after the tail own-poll left
// its retire fully exposed at the next head's vmcnt(0); r18's head-poll +
// split MFMA-B hides it better. This structure is at its latency floor:
// step ~3.1us = publish->IC-ack->flag->detect (~1.3us, two device-scope IC
// round trips inherent to cross-CU h-exchange) + partially-hidden A retire
// + stage/sync + 32 MFMA + gates. All pipes <10% utilized -- the binding
// constraint is the 1024-step serial dependency, not any resource.
//  - 192 WGs = 3 layers x (32 unit-grp x 2 batch-grp); fp16 single-plane;
//  - W_hh in regs, W_in in swizzled LDS, hbuf A/B staging;
//  - flags absolute-ts per (layer,bg); B(ts+1) register prefetch after
//    publish; head own-poll straddled by split MFMA-B; ring RR=16 with
//    8-step downstream throttle.
// ---------------------------------------------------------------------------

typedef unsigned short u16;
typedef _Float16 f16;
typedef f16 f16x8 __attribute__((ext_vector_type(8)));
typedef unsigned short ushort8 __attribute__((ext_vector_type(8)));
typedef float f32x4 __attribute__((ext_vector_type(4)));

#define NB 32
#define NT 1024
#define NH 512
#define N4H 2048
#define RR 16     // hring depth (power of 2)
#define MROWS (NB * NT)
#define HBUFB 8192  // u16 offset of operand-B buffer in hbuf

__device__ __forceinline__ float sigm(float x) { return 1.f / (1.f + __expf(-x)); }
__device__ __forceinline__ float tanh_s(float x) {
  float a = fabsf(x);
  float e = __expf(-2.f * a);
  float t = (1.f - e) / (1.f + e);
  return copysignf(t, x);
}

// --- per-instruction device-coherent (IC-level) accessors ---
__device__ __forceinline__ void ld16_sc(const u16* p, uint4& d) {
  asm volatile("global_load_dwordx4 %0, %1, off sc0 sc1" : "=v"(d) : "v"(p));
}
__device__ __forceinline__ int ldf(const int* p) {
  int r;
  asm volatile("global_load_dword %0, %1, off sc0 sc1\n\ts_waitcnt vmcnt(0)"
               : "=v"(r) : "v"(p) : "memory");
  return r;
}
__device__ __forceinline__ void st16b_sc(u16* p, unsigned v) {
  asm volatile("global_store_short %0, %1, off sc0 sc1" :: "v"(p), "v"(v) : "memory");
}
__device__ __forceinline__ void st32b_sc(int* p, int v) {
  asm volatile("global_store_dword %0, %1, off sc0 sc1" :: "v"(p), "v"(v) : "memory");
}

// X [32,4,1024,128] f32 -> xs[n=b*1024+t][512] fp16
__global__ void k_gather_x(const float* __restrict__ X, u16* __restrict__ xs) {
  int64_t i = (int64_t)blockIdx.x * 256 + threadIdx.x;  // 16,777,216
  int k = (int)(i & 511);
  int t = (int)((i >> 9) & 1023);
  int b = (int)(i >> 19);
  int c = k >> 7, f = k & 127;
  float v = X[(((int64_t)(b * 4 + c) * 1024 + t) << 7) + f];
  f16 hv = (f16)v;
  xs[((int64_t)b * 1024 + t) * 512 + k] = *(u16*)&hv;
}

// W [2048,512] f32 -> Wp[2048][512] fp16
__global__ void k_split_w(const float* __restrict__ W, u16* __restrict__ Wp) {
  int i = blockIdx.x * 256 + threadIdx.x;  // 1,048,576
  f16 hv = (f16)W[i];
  Wp[i] = *(u16*)&hv;
}

__global__ void k_bias(const float* __restrict__ bi, const float* __restrict__ bh,
                       float* __restrict__ bo) {
  int i = blockIdx.x * 256 + threadIdx.x;
  if (i < N4H) bo[i] = bi[i] + bh[i];
}

// ---------------------------------------------------------------------------
// Single-launch pipelined 3-layer LSTM, fp16. 192 WGs x 256 thr.
// wg: l=wg>>6; wgl=wg&63; bg=wgl>>5; ugg=wgl&31.  [r15..r18-verified]
// Wave w: M-tile rows tr=lane&15 -> (gate=tr&3, u_row=tr>>2); lane owns
// (unit=ugg*16+w*4+q, batch=bg*16+cb), q=lane>>4, cb=lane&15.
// Step ts: gates = bias + W_in*input(ts) + W_hh*h_l(ts-1);
//   input = xs(ts) [l=0] or hring[l-1][ts&15] [l>0], batches bg*16..+15.
// hbuf: A @0, B @HBUFB; 16 rows x 512 f16, XOR-swz by (row&7)<<3.
// wlds: W_in row r=w*16+tr at r*512 f16, elems swz by ((tr&7)<<3).
// ---------------------------------------------------------------------------
__launch_bounds__(256, 1)
__global__ void k_lstm3(const float* __restrict__ Whh0, const float* __restrict__ Whh1,
                        const float* __restrict__ Whh2,
                        const u16* __restrict__ Wp0, const u16* __restrict__ Wp1,
                        const u16* __restrict__ Wp2,
                        const float* __restrict__ bias0, const float* __restrict__ bias1,
                        const float* __restrict__ bias2,
                        const u16* __restrict__ xs, u16* __restrict__ hring,
                        u16* __restrict__ hfinal, int* __restrict__ flags) {
  __shared__ u16 wlds[32768];  // W_in fp16: 64 rows x 512, swz (64KB)
  __shared__ u16 hbuf[16384];  // A @0, B @8192: 16 rows x 512 f16, swz (32KB)
  const int tid = threadIdx.x;
  const int lane = tid & 63;
  const int w = tid >> 6;
  const int wg = blockIdx.x;
  const int l = wg >> 6;
  const int wgl = wg & 63;
  const int bg = wgl >> 5;
  const int ugg = wgl & 31;
  const int q = lane >> 4;
  const int cb = lane & 15;
  const int tr = lane & 15;

  const float* Whh = (l == 0) ? Whh0 : (l == 1) ? Whh1 : Whh2;
  const u16* Wp = (l == 0) ? Wp0 : (l == 1) ? Wp1 : Wp2;
  const float* bs = (l == 0) ? bias0 : (l == 1) ? bias1 : bias2;

  // this lane's A-row: gate=tr&3, u_row=tr>>2
  const int64_t grow = (int64_t)(tr & 3) * 512 + ugg * 16 + w * 4 + (tr >> 2);

  // --- W_hh fp16 frags into registers (64 VGPR) ---
  f16x8 whh[16];
  {
    const float* wsrc = Whh + grow * 512 + q * 8;
#pragma unroll
    for (int kk = 0; kk < 16; ++kk) {
      float4 a = *(const float4*)(wsrc + kk * 32);
      float4 b = *(const float4*)(wsrc + kk * 32 + 4);
      f16x8 hv;
      hv[0] = (f16)a.x; hv[1] = (f16)a.y; hv[2] = (f16)a.z; hv[3] = (f16)a.w;
      hv[4] = (f16)b.x; hv[5] = (f16)b.y; hv[6] = (f16)b.z; hv[7] = (f16)b.w;
      whh[kk] = hv;
    }
  }

  // --- W_in fp16 into wlds: row r=w*16+tr at r*512, elems ^((tr&7)<<3) ---
  {
#pragma unroll
    for (int i = 0; i < 16; ++i) {
      int c = tid + i * 256;          // 4096 chunks of 8 f16
      int r = c >> 6;                 // 0..63
      int kc = (c & 63) * 8;          // 0..504
      int tr2 = r & 15;
      int64_t gr = (int64_t)(tr2 & 3) * 512 + ugg * 16 + (r >> 4) * 4 + (tr2 >> 2);
      ushort8 v = *(const ushort8*)(Wp + gr * 512 + kc);
      *(ushort8*)&wlds[r * 512 + (kc ^ ((tr2 & 7) << 3))] = v;
    }
  }
  __syncthreads();

  const int bat = bg * 16 + cb;              // this lane's batch
  const int ucol = ugg * 16 + w * 4 + q;     // this lane's unit
  const float b0 = bs[ucol], b1 = bs[512 + ucol], b2 = bs[1024 + ucol],
              b3 = bs[1536 + ucol];
  float cst = 0.f;

  int* fl_own = flags + l * 64 + bg * 32;
  int* fl_up = flags + (l - 1) * 64 + bg * 32;
  int* fl_dn = flags + (l + 1) * 64 + bg * 32;
  const int wrow = (w * 16 + tr) * 512;      // lane's W_in LDS row base
  const int wswz = (tr & 7) << 3;
  const int hswz = (cb & 7) << 3;
  const int hrbA = cb * 512;
  const int hrbB = HBUFB + cb * 512;

  // per-thread staging chunk coords (4 chunks of 8 f16 each)
  int sbv[4], sov[4];
#pragma unroll
  for (int i = 0; i < 4; ++i) {
    int c = tid + i * 256;
    sbv[i] = c >> 6;
    sov[i] = (c & 63) * 8;
  }

  // --- prologue: prefetch B(0) into registers ---
  uint4 vB[4], vA[4];
  if (l > 0) {  // upstream must have published h(0)
    int gd = 0;
    for (;;) {
      if (__all((int)(ldf(fl_up + (lane & 31)) >= 1))) break;
      __builtin_amdgcn_s_sleep(1);
      if (++gd > (1 << 14)) break;
    }
    const u16* srcB = hring + ((int64_t)((l - 1) * RR) * NB + bg * 16) * 512;
#pragma unroll
    for (int i = 0; i < 4; ++i) ld16_sc(srcB + sbv[i] * 512 + sov[i], vB[i]);
  } else {
    const u16* srcB = xs + ((int64_t)(bg * 16) * NT) * 512;
#pragma unroll
    for (int i = 0; i < 4; ++i)
      ld16_sc(srcB + (int64_t)sbv[i] * NT * 512 + sov[i], vB[i]);
  }

  for (int ts = 0; ts < NT; ++ts) {
    // --- wait B(ts) (in-flight since prev publish), stage ---
    asm volatile("s_waitcnt vmcnt(0)" ::: "memory");
    __builtin_amdgcn_sched_barrier(0);
#pragma unroll
    for (int i = 0; i < 4; ++i)
      *(uint4*)&hbuf[HBUFB + sbv[i] * 512 + (sov[i] ^ ((sbv[i] & 7) << 3))] = vB[i];
    __syncthreads();

    f32x4 acc = {0.f, 0.f, 0.f, 0.f};

    // --- MFMA-B first half (poll/A-independent work before the sync) ---
#pragma unroll
    for (int kk = 0; kk < 8; ++kk) {
      const int kv = kk * 32 + q * 8;
      f16x8 wv = *(const f16x8*)&wlds[wrow + (kv ^ wswz)];
      f16x8 xv = *(const f16x8*)&hbuf[hrbB + (kv ^ hswz)];
      acc = __builtin_amdgcn_mfma_f32_16x16x32_f16(wv, xv, acc, 0, 0, 0);
    }

    // --- own-group poll (the real sync) + downstream throttle ---
    {
      const bool chk_own = (ts > 0);
      const bool chk_dn = (l < 2) && ((ts & 7) == 0);
      if (chk_own | chk_dn) {
        int gd = 0;
        for (;;) {
          int ok = 1;
          if (chk_own) ok &= (ldf(fl_own + (lane & 31)) >= ts);
          if (chk_dn) ok &= (ldf(fl_dn + (lane & 31)) >= ts - 8);
          if (__all(ok)) break;
          __builtin_amdgcn_s_sleep(1);
          if (++gd > (1 << 14)) break;  // anomaly: fail fast to wrong output
        }
      }
    }

    // --- issue A loads (own h(ts-1)); latency hidden by MFMA-B 2nd half ---
    if (ts > 0) {
      const u16* srcA = hring + ((int64_t)(l * RR + ((ts - 1) & (RR - 1))) * NB
                                 + bg * 16) * 512;
#pragma unroll
      for (int i = 0; i < 4; ++i) ld16_sc(srcA + sbv[i] * 512 + sov[i], vA[i]);
    }

    // --- MFMA-B second half (runs under A's in-flight latency) ---
#pragma unroll
    for (int kk = 8; kk < 16; ++kk) {
      const int kv = kk * 32 + q * 8;
      f16x8 wv = *(const f16x8*)&wlds[wrow + (kv ^ wswz)];
      f16x8 xv = *(const f16x8*)&hbuf[hrbB + (kv ^ hswz)];
      acc = __builtin_amdgcn_mfma_f32_16x16x32_f16(wv, xv, acc, 0, 0, 0);
    }

    // --- A phase: wait, stage, MFMA-A ---
    if (ts > 0) {
      asm volatile("s_waitcnt vmcnt(0)" ::: "memory");
      __builtin_amdgcn_sched_barrier(0);
#pragma unroll
      for (int i = 0; i < 4; ++i)
        *(uint4*)&hbuf[sbv[i] * 512 + (sov[i] ^ ((sbv[i] & 7) << 3))] = vA[i];
      __syncthreads();
#pragma unroll
      for (int kk = 0; kk < 16; ++kk) {
        const int kidx = (kk * 32 + q * 8) ^ hswz;
        f16x8 hv = *(const f16x8*)&hbuf[hrbA + kidx];
        acc = __builtin_amdgcn_mfma_f32_16x16x32_f16(whh[kk], hv, acc, 0, 0, 0);
      }
    }

    // --- gates + state ---
    float ip = acc[0] + b0;
    float fp = acc[1] + b1;
    float gg = acc[2] + b2;
    float op = acc[3] + b3;
    float i_s = sigm(ip), f_s = sigm(fp), g_t = tanh_s(gg), o_s = sigm(op);
    cst = f_s * cst + i_s * g_t;
    float h = o_s * tanh_s(cst);

    f16 hf = (f16)h;
    u16 hbits = *(u16*)&hf;
    u16* hw = hring + ((int64_t)(l * RR + (ts & (RR - 1))) * NB + bat) * 512 + ucol;
    st16b_sc(hw, (unsigned)hbits);
    if (l == 2 && ts == NT - 1) hfinal[bat * 512 + ucol] = hbits;
    asm volatile("s_waitcnt vmcnt(0)" ::: "memory");  // h at IC
    __syncthreads();  // all waves done (also fences hbuf for next step)
    if (tid == 0) st32b_sc(flags + l * 64 + bg * 32 + ugg, ts + 1);

    // --- prefetch B(ts+1): retire overlaps publish/poll of next step ---
    if (ts + 1 < NT) {
      if (l > 0) {  // need upstream h(ts+1) published (steady state: already)
        int gd = 0;
        for (;;) {
          if (__all((int)(ldf(fl_up + (lane & 31)) >= ts + 2))) break;
          __builtin_amdgcn_s_sleep(1);
          if (++gd > (1 << 14)) break;
        }
        const u16* srcB = hring + ((int64_t)((l - 1) * RR + ((ts + 1) & (RR - 1))) * NB
                                   + bg * 16) * 512;
#pragma unroll
        for (int i = 0; i < 4; ++i) ld16_sc(srcB + sbv[i] * 512 + sov[i], vB[i]);
      } else {
        const u16* srcB = xs + ((int64_t)(bg * 16) * NT + (ts + 1)) * 512;
#pragma unroll
        for (int i = 0; i < 4; ++i)
          ld16_sc(srcB + (int64_t)sbv[i] * NT * 512 + sov[i], vB[i]);
      }
    }
  }
}

// out[32,80] = hfinal(fp16) @ W_out^T + b_out
__global__ void k_final(const u16* __restrict__ hfinal, const float* __restrict__ Wout,
                        const float* __restrict__ bout, float* __restrict__ out) {
  const int b = blockIdx.x;
  const int o = threadIdx.x;
  if (o >= 80) return;
  const u16* hp = hfinal + b * 512;
  float acc = bout[o];
  for (int k = 0; k < 512; ++k) {
    f16 hv = *(const f16*)&hp[k];
    acc += (float)hv * Wout[o * 512 + k];
  }
  out[b * 80 + o] = acc;
}

extern "C" void kernel_launch(void* const* d_in, const int* in_sizes, int n_in,
                              void* d_out, int out_size, void* d_ws, size_t ws_size,
                              hipStream_t stream) {
  const float* X = (const float*)d_in[0];
  const float* Wih[3] = {(const float*)d_in[1], (const float*)d_in[5], (const float*)d_in[9]};
  const float* Whh[3] = {(const float*)d_in[2], (const float*)d_in[6], (const float*)d_in[10]};
  const float* bih[3] = {(const float*)d_in[3], (const float*)d_in[7], (const float*)d_in[11]};
  const float* bhh[3] = {(const float*)d_in[4], (const float*)d_in[8], (const float*)d_in[12]};
  const float* Wout = (const float*)d_in[13];
  const float* bout = (const float*)d_in[14];
  float* out = (float*)d_out;

  char* ws = (char*)d_ws;
  size_t off = 0;
  auto alloc = [&](size_t bytes) {
    char* p = ws + off;
    off = (off + bytes + 255) & ~(size_t)255;
    return p;
  };
  u16* xs = (u16*)alloc((size_t)MROWS * 512 * 2);          // 32 MiB
  u16* Wp[3];
  for (int l = 0; l < 3; ++l) Wp[l] = (u16*)alloc((size_t)N4H * 512 * 2);  // 2 MiB each
  float* bias[3];
  for (int l = 0; l < 3; ++l) bias[l] = (float*)alloc(N4H * 4);
  u16* hring = (u16*)alloc((size_t)3 * RR * NB * 512 * 2); // 1.5 MiB
  u16* hfinal = (u16*)alloc(NB * 512 * 2);                 // 32 KiB
  int* flags = (int*)alloc(3 * 64 * 4);                    // 768 B
  // total ~39.6 MiB

  hipMemsetAsync(flags, 0, 3 * 64 * 4, stream);
  k_gather_x<<<65536, 256, 0, stream>>>(X, xs);
  for (int l = 0; l < 3; ++l) {
    k_split_w<<<4096, 256, 0, stream>>>(Wih[l], Wp[l]);
    k_bias<<<8, 256, 0, stream>>>(bih[l], bhh[l], bias[l]);
  }

  k_lstm3<<<192, 256, 0, stream>>>(Whh[0], Whh[1], Whh[2],
                                   Wp[0], Wp[1], Wp[2],
                                   bias[0], bias[1], bias[2],
                                   xs, hring, hfinal, flags);

  k_final<<<32, 128, 0, stream>>>(hfinal, Wout, bout, out);
}